// Round 13
// baseline (50.362 us; speedup 1.0000x reference)
//
#include <hip/hip_runtime.h>

#define TK 80    // TOKEN_DIM
#define TN 384   // EMB_DIM
#define BM 64    // rows per block

typedef __attribute__((ext_vector_type(8)))  __bf16 bf16x8;
typedef __attribute__((ext_vector_type(16))) float  f32x16;

// f32 -> bf16 via compiler-native converts (v_cvt_pk_bf16_f32 pairs)
__device__ __forceinline__ bf16x8 pack8(float4 f0, float4 f1) {
    bf16x8 r;
    r[0] = (__bf16)f0.x; r[1] = (__bf16)f0.y;
    r[2] = (__bf16)f0.z; r[3] = (__bf16)f0.w;
    r[4] = (__bf16)f1.x; r[5] = (__bf16)f1.y;
    r[6] = (__bf16)f1.z; r[7] = (__bf16)f1.w;
    return r;
}

// ---------------------------------------------------------------------------
// prep: one-time W f32 -> bf16 conversion into d_ws (61.4 KB). Removes the
// 60 cvt_pk/thread W-conversion from the GEMM, which all 2048 blocks were
// redundantly paying (r11 calibration: ~40 pk-ops on prologue path ~ +3.3us).
// ---------------------------------------------------------------------------
__global__ __launch_bounds__(256) void w_conv(
    const float* __restrict__ W, __bf16* __restrict__ Wb, int n)
{
    int i = blockIdx.x * blockDim.x + threadIdx.x;
    if (i < n) Wb[i] = (__bf16)W[i];
}

// ---------------------------------------------------------------------------
// Fused TokenEmbedder — r8 structure (reproduced best, 50.2/50.4 us) with
// W loaded pre-converted (bf16x8, one 16-B load per frag, zero converts).
// Epilogue unchanged: mask/bias on dump path, pure readback+dwordx4 stores
// (r9/r10/r11 variants all regressed). No min-waves bound (r5/r6: spills).
// Block = 4 waves = 64 out rows; wave w owns out cols [96w, 96w+96).
// MFMA orientation (verified r2/r4/r8): D col = lane&31 = out col.
// ---------------------------------------------------------------------------
__global__ __launch_bounds__(256) void tok_fused(
    const float* __restrict__ feat,
    const unsigned char* __restrict__ amask,
    const int* __restrict__ gidx,
    const int* __restrict__ bidx,
    const __bf16* __restrict__ Wb,
    const float* __restrict__ bias,
    const float* __restrict__ cls,
    float* __restrict__ out,
    float* __restrict__ out_amask,
    float* __restrict__ out_gidx,
    float* __restrict__ out_bidx,
    int B, int T)
{
    // wave-private transpose tiles: [wave][mt][row][col], 32 KB total
    __shared__ __align__(16) float sT[4][2][32][32];

    const int tid   = threadIdx.x;
    const int lane  = tid & 63;
    const int wave  = tid >> 6;
    const int row0  = blockIdx.x * BM;
    const int colb  = wave * 96;
    const int lrow  = lane & 31;   // A-row (out row) / B-col (out col) in tile
    const int khalf = lane >> 5;   // 8-wide k-half selector

    // ---- amask storage detection (bool bytes vs int32): probe first 1 KB
    const unsigned int* w32 = (const unsigned int*)amask;
    unsigned int wprobe = w32[tid & 255];
    int bytemode = __syncthreads_or((int)((wprobe & 0xFFFFFF00u) != 0u));

    // ---- passthrough outputs
    if (tid < BM) {
        int r = row0 + tid;
        out_amask[r] = bytemode ? (float)amask[r] : (float)(w32[r] & 1u);
        out_bidx[r]  = (float)bidx[r];
    }
    if (blockIdx.x == 0 && tid < B) out_gidx[tid] = (float)gidx[tid];

    // ---- mask row vector: lane holds mask of row row0+lane (shfl in epilogue)
    float mv;
    {
        int r = row0 + lane;
        mv = bytemode ? (float)amask[r] : (float)(w32[r] & 1u);
    }

    // ---- A fragments: direct global loads, hoisted once, reused across nt.
    bf16x8 af[2][5];
    #pragma unroll
    for (int ks = 0; ks < 5; ++ks)
        #pragma unroll
        for (int mt = 0; mt < 2; ++mt) {
            const float* p = feat + (size_t)(row0 + mt * 32 + lrow) * TK
                           + ks * 16 + khalf * 8;
            af[mt][ks] = pack8(*(const float4*)p, *(const float4*)(p + 4));
        }

    const bool blkcls = (row0 % T) == 0;   // cls only at row rlocal==0 (BM | T)

    // ---- nt-outer: 2 accumulators live, W frags per nt (pre-converted bf16)
    #pragma unroll
    for (int nt = 0; nt < 3; ++nt) {
        const int c = colb + nt * 32 + lrow;

        bf16x8 wf[5];
        #pragma unroll
        for (int ks = 0; ks < 5; ++ks)
            wf[ks] = *(const bf16x8*)(Wb + (size_t)c * TK + ks * 16 + khalf * 8);

        f32x16 acc0 = (f32x16)0.0f, acc1 = (f32x16)0.0f;
        #pragma unroll
        for (int ks = 0; ks < 5; ++ks) {
            acc0 = __builtin_amdgcn_mfma_f32_32x32x16_bf16(af[0][ks], wf[ks], acc0, 0, 0, 0);
            acc1 = __builtin_amdgcn_mfma_f32_32x32x16_bf16(af[1][ks], wf[ks], acc1, 0, 0, 0);
        }

        const float bvn = bias[c];
        const float cvn = cls[c];

        // reg-space epilogue -> wave-private LDS tiles
        // D layout: col = lane&31, row = 4*khalf + (reg&3) + 8*(reg>>2)
        #pragma unroll
        for (int mt = 0; mt < 2; ++mt) {
            const f32x16& a = mt ? acc1 : acc0;
            #pragma unroll
            for (int reg = 0; reg < 16; ++reg) {
                const int rl = 4 * khalf + (reg & 3) + 8 * (reg >> 2);  // 0..31
                const float m = __shfl(mv, mt * 32 + rl);
                float v = m * (a[reg] + bvn);
                if (blkcls & (mt == 0) & (rl == 0)) v = cvn;
                sT[wave][mt][rl][lrow] = v;
            }
        }

        // wide read-back + dwordx4 stores
        const int rr = lane >> 3;          // 0..7
        const int cc = (lane & 7) * 4;     // 0,4,..,28
        #pragma unroll
        for (int mt = 0; mt < 2; ++mt) {
            #pragma unroll
            for (int g = 0; g < 4; ++g) {
                float4 v4 = *(const float4*)&sT[wave][mt][rr + 8 * g][cc];
                float* p = out + (size_t)(row0 + mt * 32 + rr + 8 * g) * TN
                         + colb + nt * 32 + cc;
                *(float4*)p = v4;
            }
        }
    }
}

extern "C" void kernel_launch(void* const* d_in, const int* in_sizes, int n_in,
                              void* d_out, int out_size, void* d_ws, size_t ws_size,
                              hipStream_t stream) {
    const float*         feat  = (const float*)d_in[0];
    const unsigned char* amask = (const unsigned char*)d_in[1];
    const int*           gidx  = (const int*)d_in[2];
    const int*           bidx  = (const int*)d_in[3];
    const float*         W     = (const float*)d_in[4];
    const float*         bias  = (const float*)d_in[5];
    const float*         cls   = (const float*)d_in[6];

    const int BT = in_sizes[1];        // B*T rows (131072)
    const int B  = in_sizes[2];        // 16
    const int T  = BT / B;             // 8192
    const int NW = in_sizes[4];        // EMB_DIM*TOKEN_DIM = 30720

    float* out       = (float*)d_out;                  // [BT, 384]
    float* out_amask = out + (size_t)BT * TN;          // [BT]
    float* out_gidx  = out_amask + BT;                 // [B]
    float* out_bidx  = out_gidx + B;                   // [BT]

    __bf16* Wb = (__bf16*)d_ws;                        // 61.4 KB in scratch

    w_conv<<<(NW + 255) / 256, 256, 0, stream>>>(W, Wb, NW);

    tok_fused<<<BT / BM, 256, 0, stream>>>(
        feat, amask, gidx, bidx, Wb, bias, cls,
        out, out_amask, out_gidx, out_bidx, B, T);
}